// Round 2
// baseline (5767.925 us; speedup 1.0000x reference)
//
#include <hip/hip_runtime.h>
#include <stdint.h>
#include <stddef.h>

// LSTM encoder, MI355X. 32 blocks x 16 batch rows x 512 threads (8 waves).
// Weights: bf16, gate-scale folded (+/-log2e; g: 2log2e), packed as MFMA
// B-fragments in d_ws by prep_pack. Per step: chunks 0..6 streamed L2->VGPR
// (2-deep double buffer), chunks 7..9 stationary in VGPRs (96 regs).
// h staged bf16 in LDS; c fp32 in regs; EW parity-staggered across co-SIMD
// waves so TRANS hides under the other wave's MFMAs.

typedef float f32x4 __attribute__((ext_vector_type(4)));
typedef short s16x8 __attribute__((ext_vector_type(8)));

#define T_STEPS 1000
#define IN_DIM  64
#define HID     256
#define STRIDE  328           // padded LDS row (ushorts): h[0..255] | x[256..319] | pad
#define THREADS 512
#define BT      16
#define LOG2E   1.44269504088896340736f

__device__ __forceinline__ unsigned int f2bf(float f) {
    union { float f; unsigned int u; } a; a.f = f;
    return (a.u + 0x7FFFu + ((a.u >> 16) & 1u)) >> 16;   // RNE bf16 bits
}
__device__ __forceinline__ float bf2f(unsigned short u) {
    union { float f; unsigned int u; } a; a.u = ((unsigned int)u) << 16;
    return a.f;
}

// ---------------- prep: pack scaled bf16 MFMA B-fragments -------------------
// frag fid = c*64 + w*8 + j  (c: K-chunk 0..9, w: wave, j = q*2+hp)
// lane (hi,l15) holds w[col][c*32+hi*8+e], col = q*256+w*32+hp*16+l15
__global__ void prep_pack(const float* __restrict__ w_ih,
                          const float* __restrict__ w_hh,
                          unsigned short* __restrict__ wpack) {
    const int lane = threadIdx.x;          // 64
    const int fid  = blockIdx.x;           // 640
    const int c  = fid >> 6;
    const int w  = (fid >> 3) & 7;
    const int j  = fid & 7;
    const int q  = j >> 1, hp = j & 1;
    const int l15 = lane & 15, hi = lane >> 4;
    const int col = (q << 8) | (w << 5) | (hp << 4) | l15;
    const int k0  = (c << 5) + (hi << 3);
    const float scale = (q == 2) ? (2.0f * LOG2E) : (-LOG2E);
    const float* src = (c < 8) ? (w_hh + (size_t)col * HID + k0)
                               : (w_ih + (size_t)col * IN_DIM + (k0 - HID));
    const f32x4 v0 = *reinterpret_cast<const f32x4*>(src);
    const f32x4 v1 = *reinterpret_cast<const f32x4*>(src + 4);
    s16x8 v;
    #pragma unroll
    for (int e = 0; e < 4; ++e) {
        v[e]     = (short)f2bf(scale * v0[e]);
        v[e + 4] = (short)f2bf(scale * v1[e]);
    }
    *reinterpret_cast<s16x8*>(wpack + (size_t)fid * 512 + lane * 8) = v;
}

// ---------------- fallback fragment build from f32 sources ------------------
__device__ __forceinline__ s16x8 raw_frag(const float* wh, const float* wi,
                                          int c, int w, int j, int hi, int l15) {
    const int q = j >> 1, hp = j & 1;
    const int col = (q << 8) | (w << 5) | (hp << 4) | l15;
    const int k0  = (c << 5) + (hi << 3);
    const float scale = (q == 2) ? (2.0f * LOG2E) : (-LOG2E);
    const float* src = (c < 8) ? (wh + (size_t)col * HID + k0)
                               : (wi + (size_t)col * IN_DIM + (k0 - HID));
    const f32x4 v0 = *reinterpret_cast<const f32x4*>(src);
    const f32x4 v1 = *reinterpret_cast<const f32x4*>(src + 4);
    s16x8 r;
    #pragma unroll
    for (int e = 0; e < 4; ++e) {
        r[e]     = (short)f2bf(scale * v0[e]);
        r[e + 4] = (short)f2bf(scale * v1[e]);
    }
    return r;
}

// ---------------- recurrent kernel ------------------------------------------
template<int RAW>
__global__ __launch_bounds__(THREADS, 2)
void lstm_rec(const float* __restrict__ x,
              const float* __restrict__ w_ih,
              const float* __restrict__ w_hh,
              const float* __restrict__ b_ih,
              const float* __restrict__ b_hh,
              const float* __restrict__ w_out,
              const float* __restrict__ b_out,
              const unsigned short* __restrict__ wpack,
              float* __restrict__ out)
{
    __shared__ __align__(16) unsigned short v_lds[BT][STRIDE];

    const int tid  = threadIdx.x;
    const int lane = tid & 63;
    const int w    = tid >> 6;            // wave 0..7 -> owns 128 gate cols
    const int l15  = lane & 15;
    const int hi   = lane >> 4;
    const int b0   = blockIdx.x * BT;
    const int par  = (w ^ (w >> 2)) & 1;  // co-SIMD waves get opposite parity

    // ---- stationary chunks 7,8,9 (h k224..255, x k0..63) -> 96 VGPRs
    s16x8 st7[8], st8[8], st9[8];
    #pragma unroll
    for (int j = 0; j < 8; ++j) {
        if constexpr (RAW) {
            st7[j] = raw_frag(w_hh, w_ih, 7, w, j, hi, l15);
            st8[j] = raw_frag(w_hh, w_ih, 8, w, j, hi, l15);
            st9[j] = raw_frag(w_hh, w_ih, 9, w, j, hi, l15);
        } else {
            st7[j] = *reinterpret_cast<const s16x8*>(wpack + ((size_t)(7*64 + w*8 + j))*512 + (lane<<3));
            st8[j] = *reinterpret_cast<const s16x8*>(wpack + ((size_t)(8*64 + w*8 + j))*512 + (lane<<3));
            st9[j] = *reinterpret_cast<const s16x8*>(wpack + ((size_t)(9*64 + w*8 + j))*512 + (lane<<3));
        }
    }

    // ---- scaled biases (8 per lane, one per j)
    float bias[8];
    #pragma unroll
    for (int j = 0; j < 8; ++j) {
        const int q = j >> 1, hp = j & 1;
        const int col = (q << 8) | (w << 5) | (hp << 4) | l15;
        const float scale = (q == 2) ? (2.0f * LOG2E) : (-LOG2E);
        bias[j] = scale * (b_ih[col] + b_hh[col]);
    }

    // ---- zero h staging, stage x(t=T-1)
    for (int i = tid; i < BT * STRIDE; i += THREADS)
        ((unsigned short*)v_lds)[i] = 0;
    __syncthreads();

    const int xrow = tid >> 4;            // tid<256: 16 rows x 16 threads
    const int xk   = (tid & 15) << 2;
    const float* xptr = x + (size_t)(b0 + xrow) * T_STEPS * IN_DIM + xk;
    if (tid < 256) {
        f32x4 xv0 = *reinterpret_cast<const f32x4*>(xptr + (size_t)(T_STEPS - 1) * IN_DIM);
        unsigned int p0 = f2bf(xv0[0]) | (f2bf(xv0[1]) << 16);
        unsigned int p1 = f2bf(xv0[2]) | (f2bf(xv0[3]) << 16);
        unsigned int* d = reinterpret_cast<unsigned int*>(&v_lds[xrow][HID + xk]);
        d[0] = p0; d[1] = p1;
    }
    __syncthreads();

    const unsigned short* aL = &v_lds[l15][0];   // A-frag row base

    float cst[2][4];
    #pragma unroll
    for (int a_ = 0; a_ < 2; ++a_)
        #pragma unroll
        for (int r_ = 0; r_ < 4; ++r_) cst[a_][r_] = 0.0f;

#define AF(C) (*reinterpret_cast<const s16x8*>(aL + ((C) << 5) + (hi << 3)))

#define LOADS(BUF, C) do {                                                      \
    if constexpr (RAW) {                                                        \
        _Pragma("unroll")                                                       \
        for (int j_ = 0; j_ < 8; ++j_) BUF[j_] = raw_frag(whv, wiv, (C), w, j_, hi, l15); \
    } else {                                                                    \
        _Pragma("unroll")                                                       \
        for (int j_ = 0; j_ < 8; ++j_)                                          \
            BUF[j_] = *reinterpret_cast<const s16x8*>(wpv + ((size_t)((C)*64 + w*8 + j_))*512 + (lane<<3)); \
    } } while (0)

#define CHUNK(AFV, BUF) do {                                                    \
    _Pragma("unroll")                                                           \
    for (int j_ = 0; j_ < 8; ++j_)                                              \
        acc[j_] = __builtin_amdgcn_mfma_f32_16x16x32_bf16(AFV, BUF[j_], acc[j_], 0, 0, 0); \
    } while (0)

#define POST(P) do {                                                            \
    _Pragma("unroll")                                                           \
    for (int q_ = 0; q_ < 4; ++q_) {                                            \
        const int j_ = (q_ << 1) | (P);                                         \
        acc[j_] = __builtin_amdgcn_mfma_f32_16x16x32_bf16(a7, st7[j_], acc[j_], 0, 0, 0); \
        acc[j_] = __builtin_amdgcn_mfma_f32_16x16x32_bf16(a8, st8[j_], acc[j_], 0, 0, 0); \
        acc[j_] = __builtin_amdgcn_mfma_f32_16x16x32_bf16(a9, st9[j_], acc[j_], 0, 0, 0); \
    } } while (0)

#define EW_PHASE(HP) do {                                                       \
    const int u_ = (w << 5) + ((HP) << 4) + l15;                                \
    _Pragma("unroll")                                                           \
    for (int r_ = 0; r_ < 4; ++r_) {                                            \
        const int b_ = (hi << 2) + r_;                                          \
        const float gi = acc[0 | (HP)][r_];                                     \
        const float gf = acc[2 | (HP)][r_];                                     \
        const float gg = acc[4 | (HP)][r_];                                     \
        const float go = acc[6 | (HP)][r_];                                     \
        const float si = __builtin_amdgcn_rcpf(1.0f + exp2f(gi));               \
        const float sf = __builtin_amdgcn_rcpf(1.0f + exp2f(gf));               \
        const float so = __builtin_amdgcn_rcpf(1.0f + exp2f(go));               \
        const float tg = 1.0f - 2.0f * __builtin_amdgcn_rcpf(exp2f(gg) + 1.0f); \
        float cc = cst[(HP)][r_];                                               \
        cc = sf * cc + si * tg;                                                 \
        cst[(HP)][r_] = cc;                                                     \
        const float tc = 1.0f - 2.0f * __builtin_amdgcn_rcpf(                   \
                             exp2f(2.0f * LOG2E * cc) + 1.0f);                  \
        v_lds[b_][u_] = (unsigned short)f2bf(so * tc);                          \
    } } while (0)

    f32x4 acc[8];
    #pragma unroll 1
    for (int s = 0; s < T_STEPS; ++s) {
        // Anti-LICM: perturb stream base pointers so the 56 loop-invariant
        // weight loads are NOT hoisted into (non-existent) spare registers.
        uintptr_t q0 = (uintptr_t)wpack, q1 = (uintptr_t)w_hh, q2 = (uintptr_t)w_ih;
        if constexpr (RAW) { asm volatile("" : "+v"(q1), "+v"(q2)); }
        else               { asm volatile("" : "+v"(q0)); }
        const unsigned short* wpv = (const unsigned short*)q0;
        const float* whv = (const float*)q1;
        const float* wiv = (const float*)q2;
        (void)wpv; (void)whv; (void)wiv;

        // prefetch next step's x (consumed post-D)
        int tn = T_STEPS - 2 - s; tn = (tn < 0) ? 0 : tn;
        f32x4 xv;
        if (tid < 256) xv = *reinterpret_cast<const f32x4*>(xptr + (size_t)tn * IN_DIM);

        s16x8 sb0[8], sb1[8];
        LOADS(sb0, 0); LOADS(sb1, 1);
        s16x8 a0 = AF(0), a1 = AF(1), a2 = AF(2);

        #pragma unroll
        for (int j = 0; j < 8; ++j) {
            f32x4 bb = {bias[j], bias[j], bias[j], bias[j]};
            acc[j] = bb;
        }

        CHUNK(a0, sb0); LOADS(sb0, 2);
        CHUNK(a1, sb1); LOADS(sb1, 3);
        s16x8 a3 = AF(3), a4 = AF(4);
        CHUNK(a2, sb0); LOADS(sb0, 4);
        CHUNK(a3, sb1); LOADS(sb1, 5);
        s16x8 a5 = AF(5), a6 = AF(6);
        CHUNK(a4, sb0); LOADS(sb0, 6);
        CHUNK(a5, sb1);
        s16x8 a7 = AF(7), a8 = AF(8), a9 = AF(9);
        CHUNK(a6, sb0);

        __syncthreads();   // D: all waves done reading h/x for this step

        if (par == 0) { POST(0); EW_PHASE(0); POST(1); EW_PHASE(1); }
        else          { POST(1); EW_PHASE(1); POST(0); EW_PHASE(0); }

        // stage next x into LDS
        if (tid < 256) {
            unsigned int p0 = f2bf(xv[0]) | (f2bf(xv[1]) << 16);
            unsigned int p1 = f2bf(xv[2]) | (f2bf(xv[3]) << 16);
            unsigned int* d = reinterpret_cast<unsigned int*>(&v_lds[xrow][HID + xk]);
            d[0] = p0; d[1] = p1;
        }
        __syncthreads();   // F: h(t+1), x(t+1) visible
    }

    // ---- final projection: out[b][o] = h . w_out[o] + b_out[o]
    const int o  = tid & 127;
    const int bq = tid >> 7;  // 0..3
    #pragma unroll
    for (int rb = 0; rb < 4; ++rb) {
        const int b = bq + (rb << 2);
        float a = b_out[o];
        const float* wr = w_out + (size_t)o * HID;
        #pragma unroll 8
        for (int u = 0; u < HID; u += 4) {
            f32x4 wv = *reinterpret_cast<const f32x4*>(wr + u);
            a += wv[0] * bf2f(v_lds[b][u])     + wv[1] * bf2f(v_lds[b][u + 1])
               + wv[2] * bf2f(v_lds[b][u + 2]) + wv[3] * bf2f(v_lds[b][u + 3]);
        }
        out[(size_t)(b0 + b) * 128 + o] = a;
    }
#undef AF
#undef LOADS
#undef CHUNK
#undef POST
#undef EW_PHASE
}

extern "C" void kernel_launch(void* const* d_in, const int* in_sizes, int n_in,
                              void* d_out, int out_size, void* d_ws, size_t ws_size,
                              hipStream_t stream) {
    const float* x     = (const float*)d_in[0];
    const float* w_ih  = (const float*)d_in[1];
    const float* w_hh  = (const float*)d_in[2];
    const float* b_ih  = (const float*)d_in[3];
    const float* b_hh  = (const float*)d_in[4];
    const float* w_out = (const float*)d_in[5];
    const float* b_out = (const float*)d_in[6];
    float* out = (float*)d_out;

    const bool pack = (ws_size >= (size_t)(640 * 1024));
    if (pack) {
        unsigned short* wpack = (unsigned short*)d_ws;
        hipLaunchKernelGGL(prep_pack, dim3(640), dim3(64), 0, stream, w_ih, w_hh, wpack);
        hipLaunchKernelGGL((lstm_rec<0>), dim3(512 / BT), dim3(THREADS), 0, stream,
                           x, w_ih, w_hh, b_ih, b_hh, w_out, b_out,
                           (const unsigned short*)wpack, out);
    } else {
        hipLaunchKernelGGL((lstm_rec<1>), dim3(512 / BT), dim3(THREADS), 0, stream,
                           x, w_ih, w_hh, b_ih, b_hh, w_out, b_out,
                           (const unsigned short*)nullptr, out);
    }
}